// Round 16
// baseline (454.721 us; speedup 1.0000x reference)
//
#include <hip/hip_runtime.h>
#include <hip/hip_bf16.h>

#define NRELS 4
#define MAXDEG 10
#define NBUCK 11
#define POOL_CHUNKS 8

typedef __attribute__((ext_vector_type(8))) short s16x8;
typedef __attribute__((ext_vector_type(4))) float f32x4;
typedef __attribute__((ext_vector_type(8))) unsigned short u16x8;
typedef __attribute__((ext_vector_type(4))) unsigned int u32x4;

__device__ inline unsigned short f2b(float f) {
  __hip_bfloat16 h = __float2bfloat16(f);
  return *reinterpret_cast<unsigned short*>(&h);
}
__device__ inline float b2f(unsigned short u) {
  union { unsigned int i; float f; } v;
  v.i = ((unsigned int)u) << 16;
  return v.f;
}
__device__ inline float blo(unsigned int v) {
  union { unsigned int i; float f; } x;
  x.i = v << 16;
  return x.f;
}
__device__ inline float bhi(unsigned int v) {
  union { unsigned int i; float f; } x;
  x.i = v & 0xffff0000u;
  return x.f;
}
__device__ __forceinline__ int ntl(const int* p) { return __builtin_nontemporal_load(p); }
__device__ __forceinline__ void nts16(u32x4 v, unsigned short* p) {
  __builtin_nontemporal_store(v, (u32x4*)p);
}

typedef __attribute__((address_space(3))) unsigned int lds_uint;
typedef __attribute__((address_space(1))) const unsigned int glob_uint;
__device__ __forceinline__ void gld_lds16(const void* g, void* l) {
  __builtin_amdgcn_global_load_lds((glob_uint*)g, (lds_uint*)l, 16, 0, 0);
}

// ================================================================ CSR build
// count + scan merged (last-block ticket); also grid-stride inits perm to -1.
__global__ __launch_bounds__(512) void coarse_count_scan(
    const int* __restrict__ dst, int* __restrict__ bhist, int* __restrict__ boff,
    int* __restrict__ bcur, int* __restrict__ done, int* __restrict__ perm, int permCap,
    int NB, int E, int nblocks) {
  __shared__ int lh[512];
  __shared__ int lastf;
  int t = threadIdx.x;
  lh[t] = 0;
  __syncthreads();
  for (int i = blockIdx.x * 512 + t; i < permCap; i += nblocks * 512) perm[i] = -1;
  int base = blockIdx.x * 4096;
  int lim = E - base;
  if (lim > 4096) lim = 4096;
  for (int i = t; i < lim; i += 512) atomicAdd(&lh[dst[base + i] >> 7], 1);
  __syncthreads();
  if (lh[t]) atomicAdd(&bhist[t], lh[t]);
  __threadfence();
  __syncthreads();
  if (t == 0) lastf = (atomicAdd(done, 1) == nblocks - 1) ? 1 : 0;
  __syncthreads();
  if (!lastf) return;
  int v = (t < NB) ? atomicAdd(&bhist[t], 0) : 0;
  lh[t] = v;
  __syncthreads();
  for (int o = 1; o < 512; o <<= 1) {
    int x = (t >= o) ? lh[t - o] : 0;
    __syncthreads();
    lh[t] += x;
    __syncthreads();
  }
  if (t < NB) {
    int st = lh[t] - v;
    boff[t] = st;
    bcur[t] = st;
  }
  if (t == 0) boff[NB] = E;
}

__global__ __launch_bounds__(512) void coarse_scatter(
    const int* __restrict__ src, const int* __restrict__ dst, const int* __restrict__ rel,
    int* __restrict__ bcur, uint2* __restrict__ ebuf, int E) {
  __shared__ int lhist[512];
  __shared__ int lstart[512];
  __shared__ int lcur[512];
  __shared__ int gbase[512];
  __shared__ uint2 stage[4096];
  int t = threadIdx.x;
  lhist[t] = 0;
  __syncthreads();
  int base = blockIdx.x * 4096;
  int lim = E - base;
  if (lim > 4096) lim = 4096;
  for (int i = t; i < lim; i += 512) atomicAdd(&lhist[dst[base + i] >> 7], 1);
  __syncthreads();
  int myc = lhist[t];
  lstart[t] = myc;
  __syncthreads();
  for (int o = 1; o < 512; o <<= 1) {
    int x = (t >= o) ? lstart[t - o] : 0;
    __syncthreads();
    lstart[t] += x;
    __syncthreads();
  }
  int incl = lstart[t];
  __syncthreads();
  lstart[t] = incl - myc;
  lcur[t] = 0;
  if (myc > 0) gbase[t] = atomicAdd(&bcur[t], myc);
  __syncthreads();
  for (int i = t; i < lim; i += 512) {
    int e = base + i;
    int d = dst[e];
    int b = d >> 7;
    int slot = lstart[b] + atomicAdd(&lcur[b], 1);
    stage[slot] = make_uint2((unsigned)(d * 4 + rel[e]), (unsigned)src[e]);
  }
  __syncthreads();
  for (int i = t; i < lim; i += 512) {
    uint2 val = stage[i];
    int b = (int)(val.x >> 9);
    ebuf[gbase[b] + (i - lstart[b])] = val;
  }
}

__global__ __launch_bounds__(512) void fine_place(
    const uint2* __restrict__ ebuf, const int* __restrict__ boff, int* __restrict__ cnt,
    int* __restrict__ seg_start, float* __restrict__ inv, int* __restrict__ deg,
    int* __restrict__ bucket, int* __restrict__ hist, int* __restrict__ csr, int NSEG) {
  __shared__ int lh[512];
  __shared__ int sc[512];
  __shared__ int lcur[512];
  __shared__ int lbh[16];
  int t = threadIdx.x;
  int b = blockIdx.x;
  lh[t] = 0;
  if (t < 16) lbh[t] = 0;
  __syncthreads();
  int s = boff[b], e = boff[b + 1];
  for (int i = s + t; i < e; i += 512) atomicAdd(&lh[ebuf[i].x & 511], 1);
  __syncthreads();
  int v = lh[t];
  sc[t] = v;
  __syncthreads();
  for (int o = 1; o < 512; o <<= 1) {
    int x = (t >= o) ? sc[t - o] : 0;
    __syncthreads();
    sc[t] += x;
    __syncthreads();
  }
  int gseg = b * 512 + t;
  int mystart = s + sc[t] - v;
  lcur[t] = mystart;
  if (gseg < NSEG) {
    cnt[gseg] = v;
    seg_start[gseg] = mystart;
    inv[gseg] = 1.0f / (float)(v > 1 ? v : 1);
    if ((t & 3) == 0) {
      int d = sc[t + 3] - sc[t] + v;
      int n = gseg >> 2;
      deg[n] = d;
      int bk = d < MAXDEG ? d : MAXDEG;
      bucket[n] = bk;
      atomicAdd(&lbh[bk], 1);
    }
  }
  __syncthreads();
  if (t < NBUCK && lbh[t]) atomicAdd(&hist[t], lbh[t]);
  for (int i = s + t; i < e; i += 512) {
    uint2 vv = ebuf[i];
    int pos = atomicAdd(&lcur[vv.x & 511], 1);
    csr[pos] = (int)vv.y;
  }
}

// perm build; buckets padded to 64
__global__ void build_perm(const int* __restrict__ bucket, const int* __restrict__ hist,
                           int* __restrict__ fill, int* __restrict__ perm, int N) {
  __shared__ int soff[NBUCK];
  if (threadIdx.x == 0) {
    int acc = 0;
    for (int b = 0; b < NBUCK; b++) {
      soff[b] = acc;
      acc += ((hist[b] + 63) >> 6) << 6;
    }
  }
  __syncthreads();
  int n = blockIdx.x * 256 + threadIdx.x;
  int b = (n < N) ? bucket[n] : -1;
  int lane = threadIdx.x & 63;
  for (int bb = 0; bb < NBUCK; bb++) {
    unsigned long long m = __ballot(b == bb);
    if (m == 0ULL) continue;
    int leader = __ffsll(m) - 1;
    int base = 0;
    if (lane == leader) base = atomicAdd(&fill[bb], __popcll(m));
    base = __shfl(base, leader);
    if (b == bb) {
      int idx = __popcll(m & ((1ULL << lane) - 1ULL));
      perm[soff[bb] + base + idx] = n;
    }
  }
}

// ---------------------------------------------------------------- embed (MFMA) + weight conversion, one launch
__global__ __launch_bounds__(256) void embed_conv(
    const float* __restrict__ x, const float* __restrict__ embW,
    const float* __restrict__ bias, const float* __restrict__ Wrel,
    const float* __restrict__ Wroot, const float* __restrict__ Wl,
    const float* __restrict__ Wr, unsigned short* __restrict__ Bt,
    unsigned short* __restrict__ Btm, unsigned short* __restrict__ out, int N, int nbE) {
  if ((int)blockIdx.x >= nbE) {
    const int R1 = 2 * 128 * 640;
    const int R2 = R1 + 2 * 11 * 128 * 256;
    int t = (blockIdx.x - nbE) * 256 + threadIdx.x;
    if (t < R1) {
      int blk = t / 81920;
      int rem = t % 81920;
      int n = rem / 640;
      int k = rem % 640;
      float v;
      if (k < 512)
        v = Wrel[(size_t)blk * 65536 + (size_t)k * 128 + n];
      else
        v = Wroot[(size_t)blk * 16384 + (size_t)(k - 512) * 128 + n];
      Bt[t] = f2b(v);
    } else if (t < R2) {
      int t2 = t - R1;
      int k = t2 & 255;
      int n = (t2 >> 8) & 127;
      int bb = (t2 >> 15) % 11;
      int blk = t2 / (11 * 128 * 256);
      float v;
      if (k < 128)
        v = Wl[(((size_t)blk * 11 + bb) * 128 + k) * 128 + n];
      else
        v = Wr[(((size_t)blk * 11 + bb) * 128 + (k - 128)) * 128 + n];
      Btm[t2] = f2b(v);
    }
    return;
  }
  // ---- embed path (rows padded to 80 B -> worst 2-way bank aliasing, free)
  __shared__ unsigned char As[64 * 80];
  __shared__ unsigned char Bs[128 * 80];
  int t = threadIdx.x;
  int m0 = blockIdx.x * 64;
  {
    int r = t >> 2, s = t & 3;
    int gr = m0 + r;
    if (gr >= N) gr = N - 1;
    const float* xp = x + (size_t)gr * 32 + s * 8;
    float4 f0 = *(const float4*)xp;
    float4 f1 = *(const float4*)(xp + 4);
    u16x8 o;
    o[0] = f2b(f0.x); o[1] = f2b(f0.y); o[2] = f2b(f0.z); o[3] = f2b(f0.w);
    o[4] = f2b(f1.x); o[5] = f2b(f1.y); o[6] = f2b(f1.z); o[7] = f2b(f1.w);
    *(u16x8*)(As + r * 80 + s * 16) = o;
  }
  {
    // transpose embW [32][128] fp32 -> Bs[n][k] bf16 in-kernel
    int n = t >> 1, hf = t & 1;
    unsigned short tmp[16];
#pragma unroll
    for (int j = 0; j < 16; j++) tmp[j] = f2b(embW[(size_t)(hf * 16 + j) * 128 + n]);
    *(u16x8*)(Bs + n * 80 + hf * 32) = *(u16x8*)tmp;
    *(u16x8*)(Bs + n * 80 + hf * 32 + 16) = *(u16x8*)(tmp + 8);
  }
  __syncthreads();
  int lane = t & 63, wave = t >> 6;
  int row = lane & 15, quad = lane >> 4;
  int nh = wave * 32;
  f32x4 acc[2][4];
#pragma unroll
  for (int i = 0; i < 2; i++)
#pragma unroll
    for (int j = 0; j < 4; j++) acc[i][j] = (f32x4){0.f, 0.f, 0.f, 0.f};
  s16x8 af[4], bf[2];
#pragma unroll
  for (int mt = 0; mt < 4; mt++) {
    int R = mt * 16 + row;
    af[mt] = *(const s16x8*)(As + R * 80 + quad * 16);
  }
#pragma unroll
  for (int nt = 0; nt < 2; nt++) {
    int R = nh + nt * 16 + row;
    bf[nt] = *(const s16x8*)(Bs + R * 80 + quad * 16);
  }
#pragma unroll
  for (int nt = 0; nt < 2; nt++)
#pragma unroll
    for (int mt = 0; mt < 4; mt++)
      acc[nt][mt] = __builtin_amdgcn_mfma_f32_16x16x32_bf16(af[mt], bf[nt], acc[nt][mt], 0, 0, 0);
#pragma unroll
  for (int nt = 0; nt < 2; nt++) {
    int n = nh + nt * 16 + row;
    float bv = bias[n];
#pragma unroll
    for (int mt = 0; mt < 4; mt++) {
#pragma unroll
      for (int r4 = 0; r4 < 4; r4++) {
        int m = m0 + mt * 16 + quad * 4 + r4;
        if (m < N) out[(size_t)m * 128 + n] = f2b(acc[nt][mt][r4] + bv);
      }
    }
  }
}

// ---------------------------------------------------------------- gathers
// nontemporal csr loads (zero reuse) + nontemporal output stores: keep h resident in L2.
#define ACC8(v)                                   \
  do {                                            \
    a0 += blo((v).x); a1 += bhi((v).x);           \
    a2 += blo((v).y); a3 += bhi((v).y);           \
    a4 += blo((v).z); a5 += bhi((v).z);           \
    a6 += blo((v).w); a7 += bhi((v).w);           \
  } while (0)

__global__ __launch_bounds__(256) void rgcn_gather(
    const unsigned short* __restrict__ hb, const int* __restrict__ csr,
    const int* __restrict__ seg_start, const int* __restrict__ cnt,
    const float* __restrict__ inv, const int* __restrict__ perm,
    unsigned short* __restrict__ ahat, int total) {
  int half = blockIdx.x & 1;
  int i = (blockIdx.x >> 1) * 32 + (threadIdx.x >> 3);
  if (i >= total) return;
  int n = perm[i];
  if (n < 0) return;
  int c8 = half * 64 + (threadIdx.x & 7) * 8;
  int4 st4 = *(const int4*)(seg_start + (size_t)n * 4);
  int4 cn4 = *(const int4*)(cnt + (size_t)n * 4);
  float4 w4 = *(const float4*)(inv + (size_t)n * 4);
  int sts[4] = {st4.x, st4.y, st4.z, st4.w};
  int cns[4] = {cn4.x, cn4.y, cn4.z, cn4.w};
  float ws[4] = {w4.x, w4.y, w4.z, w4.w};
#pragma unroll
  for (int r = 0; r < 4; r++) {
    int st = sts[r], cn = cns[r];
    float w = ws[r];
    float a0 = 0.f, a1 = 0.f, a2 = 0.f, a3 = 0.f, a4 = 0.f, a5 = 0.f, a6 = 0.f, a7 = 0.f;
    int ii = 0;
    for (; ii + 4 <= cn; ii += 4) {
      int p0 = ntl(csr + st + ii), p1 = ntl(csr + st + ii + 1);
      int p2 = ntl(csr + st + ii + 2), p3 = ntl(csr + st + ii + 3);
      uint4 v0 = *(const uint4*)(hb + (size_t)p0 * 128 + c8);
      uint4 v1 = *(const uint4*)(hb + (size_t)p1 * 128 + c8);
      uint4 v2 = *(const uint4*)(hb + (size_t)p2 * 128 + c8);
      uint4 v3 = *(const uint4*)(hb + (size_t)p3 * 128 + c8);
      ACC8(v0);
      ACC8(v1);
      ACC8(v2);
      ACC8(v3);
    }
    if (ii + 2 <= cn) {
      int p0 = ntl(csr + st + ii), p1 = ntl(csr + st + ii + 1);
      uint4 v0 = *(const uint4*)(hb + (size_t)p0 * 128 + c8);
      uint4 v1 = *(const uint4*)(hb + (size_t)p1 * 128 + c8);
      ACC8(v0);
      ACC8(v1);
      ii += 2;
    }
    if (ii < cn) {
      uint4 v0 = *(const uint4*)(hb + (size_t)ntl(csr + st + ii) * 128 + c8);
      ACC8(v0);
    }
    u32x4 o;
    o.x = (unsigned int)f2b(a0 * w) | ((unsigned int)f2b(a1 * w) << 16);
    o.y = (unsigned int)f2b(a2 * w) | ((unsigned int)f2b(a3 * w) << 16);
    o.z = (unsigned int)f2b(a4 * w) | ((unsigned int)f2b(a5 * w) << 16);
    o.w = (unsigned int)f2b(a6 * w) | ((unsigned int)f2b(a7 * w) << 16);
    nts16(o, ahat + (size_t)i * 512 + r * 128 + c8);
  }
}

__global__ __launch_bounds__(256) void mf_gather(
    const unsigned short* __restrict__ hb, const int* __restrict__ csr,
    const int* __restrict__ seg_start, const int* __restrict__ deg,
    const int* __restrict__ perm, unsigned short* __restrict__ amf, int total) {
  int half = blockIdx.x & 1;
  int i = (blockIdx.x >> 1) * 32 + (threadIdx.x >> 3);
  if (i >= total) return;
  int n = perm[i];
  if (n < 0) return;
  int c8 = half * 64 + (threadIdx.x & 7) * 8;
  int st = seg_start[n * 4], dg = deg[n];
  float a0 = 0.f, a1 = 0.f, a2 = 0.f, a3 = 0.f, a4 = 0.f, a5 = 0.f, a6 = 0.f, a7 = 0.f;
  int i2 = 0;
  for (; i2 + 4 <= dg; i2 += 4) {
    int p0 = ntl(csr + st + i2), p1 = ntl(csr + st + i2 + 1);
    int p2 = ntl(csr + st + i2 + 2), p3 = ntl(csr + st + i2 + 3);
    uint4 v0 = *(const uint4*)(hb + (size_t)p0 * 128 + c8);
    uint4 v1 = *(const uint4*)(hb + (size_t)p1 * 128 + c8);
    uint4 v2 = *(const uint4*)(hb + (size_t)p2 * 128 + c8);
    uint4 v3 = *(const uint4*)(hb + (size_t)p3 * 128 + c8);
    ACC8(v0);
    ACC8(v1);
    ACC8(v2);
    ACC8(v3);
  }
  if (i2 + 2 <= dg) {
    int p0 = ntl(csr + st + i2), p1 = ntl(csr + st + i2 + 1);
    uint4 v0 = *(const uint4*)(hb + (size_t)p0 * 128 + c8);
    uint4 v1 = *(const uint4*)(hb + (size_t)p1 * 128 + c8);
    ACC8(v0);
    ACC8(v1);
    i2 += 2;
  }
  if (i2 < dg) {
    uint4 v0 = *(const uint4*)(hb + (size_t)ntl(csr + st + i2) * 128 + c8);
    ACC8(v0);
  }
  u32x4 o;
  o.x = (unsigned int)f2b(a0) | ((unsigned int)f2b(a1) << 16);
  o.y = (unsigned int)f2b(a2) | ((unsigned int)f2b(a3) << 16);
  o.z = (unsigned int)f2b(a4) | ((unsigned int)f2b(a5) << 16);
  o.w = (unsigned int)f2b(a6) | ((unsigned int)f2b(a7) << 16);
  nts16(o, amf + (size_t)i * 128 + c8);
}

// ---------------------------------------------------------------- tiled MFMA GEMMs (64-row blocks)
__global__ __launch_bounds__(256) void rgcn_mfma(const unsigned short* __restrict__ A,
                                                 const unsigned short* __restrict__ hroot,
                                                 const unsigned short* __restrict__ Bt,
                                                 const float* __restrict__ bias,
                                                 const int* __restrict__ perm,
                                                 unsigned short* __restrict__ out) {
  __shared__ unsigned char As[8192];
  __shared__ unsigned char Bs[16384];
  __shared__ int nodes[64];
  int t = threadIdx.x;
  int m0 = blockIdx.x * 64;
  if (t >= 64 && t < 128) nodes[t - 64] = perm[m0 + t - 64];
  __syncthreads();
  int lane = t & 63, wave = t >> 6;
  int row = lane & 15, quad = lane >> 4;
  int nh = wave * 32;
  f32x4 acc[2][4];
#pragma unroll
  for (int i = 0; i < 2; i++)
#pragma unroll
    for (int j = 0; j < 4; j++) acc[i][j] = (f32x4){0.f, 0.f, 0.f, 0.f};

  for (int kt = 0; kt < 10; kt++) {
    int kb2 = kt * 128;
#pragma unroll
    for (int s = 0; s < 2; s++) {
      int o = s * 4096 + t * 16;
      int r = o >> 7, c = ((o >> 4) & 7) ^ (r & 7);
      const char* gsrc;
      if (kt < 8) {
        gsrc = (const char*)A + (size_t)(m0 + r) * 1024 + kb2 + c * 16;
      } else {
        int nd = nodes[r];
        if (nd < 0) nd = 0;
        gsrc = (const char*)hroot + (size_t)nd * 256 + (kb2 - 1024) + c * 16;
      }
      gld_lds16(gsrc, As + o);
    }
#pragma unroll
    for (int s = 0; s < 4; s++) {
      int o = s * 4096 + t * 16;
      int r = o >> 7, c = ((o >> 4) & 7) ^ (r & 7);
      gld_lds16((const char*)Bt + (size_t)r * 1280 + kb2 + c * 16, Bs + o);
    }
    __syncthreads();
#pragma unroll
    for (int ks = 0; ks < 2; ks++) {
      int cch = ks * 4 + quad;
      s16x8 af[4], bf[2];
#pragma unroll
      for (int mt = 0; mt < 4; mt++) {
        int R = mt * 16 + row;
        af[mt] = *(const s16x8*)(As + R * 128 + ((cch ^ (R & 7)) << 4));
      }
#pragma unroll
      for (int nt = 0; nt < 2; nt++) {
        int R = nh + nt * 16 + row;
        bf[nt] = *(const s16x8*)(Bs + R * 128 + ((cch ^ (R & 7)) << 4));
      }
#pragma unroll
      for (int nt = 0; nt < 2; nt++)
#pragma unroll
        for (int mt = 0; mt < 4; mt++)
          acc[nt][mt] = __builtin_amdgcn_mfma_f32_16x16x32_bf16(af[mt], bf[nt], acc[nt][mt], 0, 0, 0);
    }
    __syncthreads();
  }
#pragma unroll
  for (int nt = 0; nt < 2; nt++) {
    int n = nh + nt * 16 + row;
    float bv = bias[n];
#pragma unroll
    for (int mt = 0; mt < 4; mt++) {
#pragma unroll
      for (int r4 = 0; r4 < 4; r4++) {
        int nd = nodes[mt * 16 + quad * 4 + r4];
        if (nd >= 0) out[(size_t)nd * 128 + n] = f2b(fmaxf(acc[nt][mt][r4] + bv, 0.f));
      }
    }
  }
}

__global__ __launch_bounds__(256) void mf_mfma(const unsigned short* __restrict__ A,
                                               const unsigned short* __restrict__ hroot,
                                               const unsigned short* __restrict__ Bt,
                                               const float* __restrict__ bl,
                                               const int* __restrict__ perm,
                                               const int* __restrict__ hist,
                                               unsigned short* __restrict__ out, int relu_out) {
  __shared__ unsigned char As[8192];
  __shared__ unsigned char Bs[16384];
  __shared__ int soff[NBUCK + 1];
  __shared__ int nodes[64];
  int t = threadIdx.x;
  int m0 = blockIdx.x * 64;
  if (t == 0) {
    int acc = 0;
    for (int b2 = 0; b2 < NBUCK; b2++) {
      soff[b2] = acc;
      acc += ((hist[b2] + 63) >> 6) << 6;
    }
    soff[NBUCK] = acc;
  }
  if (t >= 64 && t < 128) nodes[t - 64] = perm[m0 + t - 64];
  __syncthreads();
  if (m0 >= soff[NBUCK]) return;
  int b = 0;
  while (b < 10 && m0 >= soff[b + 1]) b++;
  const unsigned short* Bb = Bt + (size_t)b * 128 * 256;
  const float* bb = bl + b * 128;
  int lane = t & 63, wave = t >> 6;
  int row = lane & 15, quad = lane >> 4;
  int nh = wave * 32;
  f32x4 acc[2][4];
#pragma unroll
  for (int i = 0; i < 2; i++)
#pragma unroll
    for (int j = 0; j < 4; j++) acc[i][j] = (f32x4){0.f, 0.f, 0.f, 0.f};

  for (int kt = 0; kt < 4; kt++) {
    int kb2 = kt * 128;
#pragma unroll
    for (int s = 0; s < 2; s++) {
      int o = s * 4096 + t * 16;
      int r = o >> 7, c = ((o >> 4) & 7) ^ (r & 7);
      const char* gsrc;
      if (kt < 2) {
        gsrc = (const char*)A + (size_t)(m0 + r) * 256 + kb2 + c * 16;
      } else {
        int nd = nodes[r];
        if (nd < 0) nd = 0;
        gsrc = (const char*)hroot + (size_t)nd * 256 + (kb2 - 512) + c * 16;
      }
      gld_lds16(gsrc, As + o);
    }
#pragma unroll
    for (int s = 0; s < 4; s++) {
      int o = s * 4096 + t * 16;
      int r = o >> 7, c = ((o >> 4) & 7) ^ (r & 7);
      gld_lds16((const char*)Bb + (size_t)r * 512 + kb2 + c * 16, Bs + o);
    }
    __syncthreads();
#pragma unroll
    for (int ks = 0; ks < 2; ks++) {
      int cch = ks * 4 + quad;
      s16x8 af[4], bf[2];
#pragma unroll
      for (int mt = 0; mt < 4; mt++) {
        int R = mt * 16 + row;
        af[mt] = *(const s16x8*)(As + R * 128 + ((cch ^ (R & 7)) << 4));
      }
#pragma unroll
      for (int nt = 0; nt < 2; nt++) {
        int R = nh + nt * 16 + row;
        bf[nt] = *(const s16x8*)(Bs + R * 128 + ((cch ^ (R & 7)) << 4));
      }
#pragma unroll
      for (int nt = 0; nt < 2; nt++)
#pragma unroll
        for (int mt = 0; mt < 4; mt++)
          acc[nt][mt] = __builtin_amdgcn_mfma_f32_16x16x32_bf16(af[mt], bf[nt], acc[nt][mt], 0, 0, 0);
    }
    __syncthreads();
  }
#pragma unroll
  for (int nt = 0; nt < 2; nt++) {
    int n = nh + nt * 16 + row;
    float bv = bb[n];
#pragma unroll
    for (int mt = 0; mt < 4; mt++) {
#pragma unroll
      for (int r4 = 0; r4 < 4; r4++) {
        int nd = nodes[mt * 16 + quad * 4 + r4];
        if (nd >= 0) {
          float v = acc[nt][mt][r4] + bv;
          if (relu_out) v = fmaxf(v, 0.f);
          out[(size_t)nd * 128 + n] = f2b(v);
        }
      }
    }
  }
}

// ---------------------------------------------------------------- pool + head
__global__ void pool2(const unsigned short* __restrict__ h, const int* __restrict__ batch,
                      float* __restrict__ g, int N, int G) {
  int gr = blockIdx.x / POOL_CHUNKS;
  int ck = blockIdx.x % POOL_CHUNKS;
  int t = threadIdx.x;
  int lane = t & 63, grp = t >> 6;
  int lo = 0, hi = N;
  while (lo < hi) {
    int m = (lo + hi) >> 1;
    if (batch[m] < gr) lo = m + 1; else hi = m;
  }
  int s = lo;
  lo = s; hi = N;
  while (lo < hi) {
    int m = (lo + hi) >> 1;
    if (batch[m] < gr + 1) lo = m + 1; else hi = m;
  }
  int e = lo;
  int len = e - s;
  int a = s + (int)(((long long)len * ck) / POOL_CHUNKS);
  int b = s + (int)(((long long)len * (ck + 1)) / POOL_CHUNKS);
  float s0 = 0.f, s1 = 0.f;
  for (int n = a + grp; n < b; n += 2) {
    unsigned int v = *(const unsigned int*)(h + (size_t)n * 128 + lane * 2);
    s0 += blo(v);
    s1 += bhi(v);
  }
  if (b > a + grp) {
    atomicAdd(&g[gr * 128 + lane * 2], s0);
    atomicAdd(&g[gr * 128 + lane * 2 + 1], s1);
  }
}

__global__ void head_kernel(const float* __restrict__ g, const float* __restrict__ W1,
                            const float* __restrict__ b1, const float* __restrict__ W2,
                            const float* __restrict__ b2, float* __restrict__ out) {
  int bg = blockIdx.x;
  int o = threadIdx.x;
  __shared__ float gs[128];
  __shared__ float red[128];
  gs[o] = g[bg * 128 + o];
  __syncthreads();
  float acc = b1[o];
  for (int k = 0; k < 128; k++) acc += gs[k] * W1[k * 128 + o];
  acc = fmaxf(acc, 0.f);
  red[o] = acc * W2[o];
  __syncthreads();
  for (int s = 64; s > 0; s >>= 1) {
    if (o < s) red[o] += red[o + s];
    __syncthreads();
  }
  if (o == 0) out[bg] = red[0] + b2[0];
}

// ---------------------------------------------------------------- launch
extern "C" void kernel_launch(void* const* d_in, const int* in_sizes, int n_in,
                              void* d_out, int out_size, void* d_ws, size_t ws_size,
                              hipStream_t stream) {
  const float* x = (const float*)d_in[0];
  const int* ei = (const int*)d_in[1];
  const int* ea = (const int*)d_in[2];
  const int* batch = (const int*)d_in[3];
  const float* embW = (const float*)d_in[4];
  const float* embB = (const float*)d_in[5];
  const float* Wrel = (const float*)d_in[6];
  const float* Wroot = (const float*)d_in[7];
  const float* rb = (const float*)d_in[8];
  const float* Wl = (const float*)d_in[9];
  const float* bl = (const float*)d_in[10];
  const float* Wr = (const float*)d_in[11];
  const float* l1W = (const float*)d_in[12];
  const float* l1b = (const float*)d_in[13];
  const float* l2W = (const float*)d_in[14];
  const float* l2b = (const float*)d_in[15];
  float* out = (float*)d_out;

  int N = in_sizes[0] / 32;
  int E = in_sizes[2];
  int G = out_size;
  int NSEG = N * 4;
  int NB = (N + 127) >> 7;

  char* p = (char*)d_ws;
  auto alloc = [&](size_t bytes) {
    char* r = p;
    p += (bytes + 255) & ~(size_t)255;
    return r;
  };
  int permCap = ((N + 63) / 64 + NBUCK) * 64;
  unsigned short* h_bf = (unsigned short*)alloc((size_t)N * 128 * 2);
  unsigned short* h2_bf = (unsigned short*)alloc((size_t)N * 128 * 2);
  unsigned short* ahat = (unsigned short*)alloc((size_t)permCap * 512 * 2);
  unsigned short* amf = (unsigned short*)alloc((size_t)permCap * 128 * 2);
  unsigned short* Btr = (unsigned short*)alloc((size_t)2 * 128 * 640 * 2);
  unsigned short* Btm = (unsigned short*)alloc((size_t)2 * 11 * 128 * 256 * 2);
  float* inv = (float*)alloc((size_t)NSEG * 4);
  int* cnt = (int*)alloc((size_t)NSEG * 4);
  int* seg_start = (int*)alloc((size_t)NSEG * 4);
  int* csr = (int*)alloc((size_t)E * 4);
  uint2* ebuf = (uint2*)alloc((size_t)E * 8);
  int* deg = (int*)alloc((size_t)N * 4);
  int* bucket = (int*)alloc((size_t)N * 4);
  int* perm = (int*)alloc((size_t)permCap * 4);
  int* boff = (int*)alloc(516 * 4);
  int* bcur = (int*)alloc(512 * 4);
  size_t zeroBytes = 8192 + (size_t)G * 128 * 4;
  char* zb = alloc(zeroBytes);
  int* bhist = (int*)zb;
  int* hist = (int*)(zb + 4096);
  int* fill = (int*)(zb + 4224);
  int* done = (int*)(zb + 4352);
  float* g = (float*)(zb + 8192);

  (void)hipMemsetAsync(zb, 0, zeroBytes, stream);

  const int* src = ei;
  const int* dst = ei + E;

  int sblocks = (E + 4095) / 4096;
  coarse_count_scan<<<sblocks, 512, 0, stream>>>(dst, bhist, boff, bcur, done, perm, permCap,
                                                 NB, E, sblocks);
  coarse_scatter<<<sblocks, 512, 0, stream>>>(src, dst, ea, bcur, ebuf, E);
  fine_place<<<NB, 512, 0, stream>>>(ebuf, boff, cnt, seg_start, inv, deg, bucket, hist, csr,
                                     NSEG);
  build_perm<<<(N + 255) / 256, 256, 0, stream>>>(bucket, hist, fill, perm, N);

  int nbE = (N + 63) / 64;
  int convBlocks = (2 * 128 * 640 + 2 * 11 * 128 * 256 + 255) / 256;
  embed_conv<<<nbE + convBlocks, 256, 0, stream>>>(x, embW, embB, Wrel, Wroot, Wl, Wr, Btr,
                                                   Btm, h_bf, N, nbE);

  int mfblocks = permCap / 64;
  int gblocks = ((permCap + 31) / 32) * 2;
  for (int blk = 0; blk < 2; blk++) {
    rgcn_gather<<<gblocks, 256, 0, stream>>>(h_bf, csr, seg_start, cnt, inv, perm, ahat,
                                             permCap);
    rgcn_mfma<<<mfblocks, 256, 0, stream>>>(ahat, h_bf, Btr + (size_t)blk * 81920,
                                            rb + blk * 128, perm, h2_bf);
    mf_gather<<<gblocks, 256, 0, stream>>>(h2_bf, csr, seg_start, deg, perm, amf, permCap);
    mf_mfma<<<mfblocks, 256, 0, stream>>>(amf, h2_bf, Btm + (size_t)blk * 11 * 128 * 256,
                                          bl + (size_t)blk * 11 * 128, perm, hist, h_bf,
                                          (blk == 0) ? 1 : 0);
  }
  pool2<<<G * POOL_CHUNKS, 128, 0, stream>>>(h_bf, batch, g, N, G);
  head_kernel<<<G, 128, 0, stream>>>(g, l1W, l1b, l2W, l2b, out);
}

// Round 17
// 396.994 us; speedup vs baseline: 1.1454x; 1.1454x over previous
//
#include <hip/hip_runtime.h>
#include <hip/hip_bf16.h>

#define NRELS 4
#define MAXDEG 10
#define NBUCK 11
#define POOL_CHUNKS 8

typedef __attribute__((ext_vector_type(8))) short s16x8;
typedef __attribute__((ext_vector_type(4))) float f32x4;
typedef __attribute__((ext_vector_type(8))) unsigned short u16x8;

__device__ inline unsigned short f2b(float f) {
  __hip_bfloat16 h = __float2bfloat16(f);
  return *reinterpret_cast<unsigned short*>(&h);
}
__device__ inline float b2f(unsigned short u) {
  union { unsigned int i; float f; } v;
  v.i = ((unsigned int)u) << 16;
  return v.f;
}
__device__ inline float blo(unsigned int v) {
  union { unsigned int i; float f; } x;
  x.i = v << 16;
  return x.f;
}
__device__ inline float bhi(unsigned int v) {
  union { unsigned int i; float f; } x;
  x.i = v & 0xffff0000u;
  return x.f;
}

typedef __attribute__((address_space(3))) unsigned int lds_uint;
typedef __attribute__((address_space(1))) const unsigned int glob_uint;
__device__ __forceinline__ void gld_lds16(const void* g, void* l) {
  __builtin_amdgcn_global_load_lds((glob_uint*)g, (lds_uint*)l, 16, 0, 0);
}

// ================================================================ CSR build
// count + scan merged (last-block ticket); also grid-stride inits perm to -1.
__global__ __launch_bounds__(512) void coarse_count_scan(
    const int* __restrict__ dst, int* __restrict__ bhist, int* __restrict__ boff,
    int* __restrict__ bcur, int* __restrict__ done, int* __restrict__ perm, int permCap,
    int NB, int E, int nblocks) {
  __shared__ int lh[512];
  __shared__ int lastf;
  int t = threadIdx.x;
  lh[t] = 0;
  __syncthreads();
  for (int i = blockIdx.x * 512 + t; i < permCap; i += nblocks * 512) perm[i] = -1;
  int base = blockIdx.x * 4096;
  int lim = E - base;
  if (lim > 4096) lim = 4096;
  for (int i = t; i < lim; i += 512) atomicAdd(&lh[dst[base + i] >> 7], 1);
  __syncthreads();
  if (lh[t]) atomicAdd(&bhist[t], lh[t]);
  __threadfence();
  __syncthreads();
  if (t == 0) lastf = (atomicAdd(done, 1) == nblocks - 1) ? 1 : 0;
  __syncthreads();
  if (!lastf) return;
  int v = (t < NB) ? atomicAdd(&bhist[t], 0) : 0;
  lh[t] = v;
  __syncthreads();
  for (int o = 1; o < 512; o <<= 1) {
    int x = (t >= o) ? lh[t - o] : 0;
    __syncthreads();
    lh[t] += x;
    __syncthreads();
  }
  if (t < NB) {
    int st = lh[t] - v;
    boff[t] = st;
    bcur[t] = st;
  }
  if (t == 0) boff[NB] = E;
}

__global__ __launch_bounds__(512) void coarse_scatter(
    const int* __restrict__ src, const int* __restrict__ dst, const int* __restrict__ rel,
    int* __restrict__ bcur, uint2* __restrict__ ebuf, int E) {
  __shared__ int lhist[512];
  __shared__ int lstart[512];
  __shared__ int lcur[512];
  __shared__ int gbase[512];
  __shared__ uint2 stage[4096];
  int t = threadIdx.x;
  lhist[t] = 0;
  __syncthreads();
  int base = blockIdx.x * 4096;
  int lim = E - base;
  if (lim > 4096) lim = 4096;
  for (int i = t; i < lim; i += 512) atomicAdd(&lhist[dst[base + i] >> 7], 1);
  __syncthreads();
  int myc = lhist[t];
  lstart[t] = myc;
  __syncthreads();
  for (int o = 1; o < 512; o <<= 1) {
    int x = (t >= o) ? lstart[t - o] : 0;
    __syncthreads();
    lstart[t] += x;
    __syncthreads();
  }
  int incl = lstart[t];
  __syncthreads();
  lstart[t] = incl - myc;
  lcur[t] = 0;
  if (myc > 0) gbase[t] = atomicAdd(&bcur[t], myc);
  __syncthreads();
  for (int i = t; i < lim; i += 512) {
    int e = base + i;
    int d = dst[e];
    int b = d >> 7;
    int slot = lstart[b] + atomicAdd(&lcur[b], 1);
    stage[slot] = make_uint2((unsigned)(d * 4 + rel[e]), (unsigned)src[e]);
  }
  __syncthreads();
  for (int i = t; i < lim; i += 512) {
    uint2 val = stage[i];
    int b = (int)(val.x >> 9);
    ebuf[gbase[b] + (i - lstart[b])] = val;
  }
}

__global__ __launch_bounds__(512) void fine_place(
    const uint2* __restrict__ ebuf, const int* __restrict__ boff, int* __restrict__ cnt,
    int* __restrict__ seg_start, float* __restrict__ inv, int* __restrict__ deg,
    int* __restrict__ bucket, int* __restrict__ hist, int* __restrict__ csr, int NSEG) {
  __shared__ int lh[512];
  __shared__ int sc[512];
  __shared__ int lcur[512];
  __shared__ int lbh[16];
  int t = threadIdx.x;
  int b = blockIdx.x;
  lh[t] = 0;
  if (t < 16) lbh[t] = 0;
  __syncthreads();
  int s = boff[b], e = boff[b + 1];
  for (int i = s + t; i < e; i += 512) atomicAdd(&lh[ebuf[i].x & 511], 1);
  __syncthreads();
  int v = lh[t];
  sc[t] = v;
  __syncthreads();
  for (int o = 1; o < 512; o <<= 1) {
    int x = (t >= o) ? sc[t - o] : 0;
    __syncthreads();
    sc[t] += x;
    __syncthreads();
  }
  int gseg = b * 512 + t;
  int mystart = s + sc[t] - v;
  lcur[t] = mystart;
  if (gseg < NSEG) {
    cnt[gseg] = v;
    seg_start[gseg] = mystart;
    inv[gseg] = 1.0f / (float)(v > 1 ? v : 1);
    if ((t & 3) == 0) {
      int d = sc[t + 3] - sc[t] + v;
      int n = gseg >> 2;
      deg[n] = d;
      int bk = d < MAXDEG ? d : MAXDEG;
      bucket[n] = bk;
      atomicAdd(&lbh[bk], 1);
    }
  }
  __syncthreads();
  if (t < NBUCK && lbh[t]) atomicAdd(&hist[t], lbh[t]);
  for (int i = s + t; i < e; i += 512) {
    uint2 vv = ebuf[i];
    int pos = atomicAdd(&lcur[vv.x & 511], 1);
    csr[pos] = (int)vv.y;
  }
}

// perm build; buckets padded to 64
__global__ void build_perm(const int* __restrict__ bucket, const int* __restrict__ hist,
                           int* __restrict__ fill, int* __restrict__ perm, int N) {
  __shared__ int soff[NBUCK];
  if (threadIdx.x == 0) {
    int acc = 0;
    for (int b = 0; b < NBUCK; b++) {
      soff[b] = acc;
      acc += ((hist[b] + 63) >> 6) << 6;
    }
  }
  __syncthreads();
  int n = blockIdx.x * 256 + threadIdx.x;
  int b = (n < N) ? bucket[n] : -1;
  int lane = threadIdx.x & 63;
  for (int bb = 0; bb < NBUCK; bb++) {
    unsigned long long m = __ballot(b == bb);
    if (m == 0ULL) continue;
    int leader = __ffsll(m) - 1;
    int base = 0;
    if (lane == leader) base = atomicAdd(&fill[bb], __popcll(m));
    base = __shfl(base, leader);
    if (b == bb) {
      int idx = __popcll(m & ((1ULL << lane) - 1ULL));
      perm[soff[bb] + base + idx] = n;
    }
  }
}

// ---------------------------------------------------------------- embed (MFMA) + weight conversion, one launch
__global__ __launch_bounds__(256) void embed_conv(
    const float* __restrict__ x, const float* __restrict__ embW,
    const float* __restrict__ bias, const float* __restrict__ Wrel,
    const float* __restrict__ Wroot, const float* __restrict__ Wl,
    const float* __restrict__ Wr, unsigned short* __restrict__ Bt,
    unsigned short* __restrict__ Btm, unsigned short* __restrict__ out, int N, int nbE) {
  if ((int)blockIdx.x >= nbE) {
    const int R1 = 2 * 128 * 640;
    const int R2 = R1 + 2 * 11 * 128 * 256;
    int t = (blockIdx.x - nbE) * 256 + threadIdx.x;
    if (t < R1) {
      int blk = t / 81920;
      int rem = t % 81920;
      int n = rem / 640;
      int k = rem % 640;
      float v;
      if (k < 512)
        v = Wrel[(size_t)blk * 65536 + (size_t)k * 128 + n];
      else
        v = Wroot[(size_t)blk * 16384 + (size_t)(k - 512) * 128 + n];
      Bt[t] = f2b(v);
    } else if (t < R2) {
      int t2 = t - R1;
      int k = t2 & 255;
      int n = (t2 >> 8) & 127;
      int bb = (t2 >> 15) % 11;
      int blk = t2 / (11 * 128 * 256);
      float v;
      if (k < 128)
        v = Wl[(((size_t)blk * 11 + bb) * 128 + k) * 128 + n];
      else
        v = Wr[(((size_t)blk * 11 + bb) * 128 + (k - 128)) * 128 + n];
      Btm[t2] = f2b(v);
    }
    return;
  }
  __shared__ unsigned char As[64 * 80];
  __shared__ unsigned char Bs[128 * 80];
  int t = threadIdx.x;
  int m0 = blockIdx.x * 64;
  {
    int r = t >> 2, s = t & 3;
    int gr = m0 + r;
    if (gr >= N) gr = N - 1;
    const float* xp = x + (size_t)gr * 32 + s * 8;
    float4 f0 = *(const float4*)xp;
    float4 f1 = *(const float4*)(xp + 4);
    u16x8 o;
    o[0] = f2b(f0.x); o[1] = f2b(f0.y); o[2] = f2b(f0.z); o[3] = f2b(f0.w);
    o[4] = f2b(f1.x); o[5] = f2b(f1.y); o[6] = f2b(f1.z); o[7] = f2b(f1.w);
    *(u16x8*)(As + r * 80 + s * 16) = o;
  }
  {
    int n = t >> 1, hf = t & 1;
    unsigned short tmp[16];
#pragma unroll
    for (int j = 0; j < 16; j++) tmp[j] = f2b(embW[(size_t)(hf * 16 + j) * 128 + n]);
    *(u16x8*)(Bs + n * 80 + hf * 32) = *(u16x8*)tmp;
    *(u16x8*)(Bs + n * 80 + hf * 32 + 16) = *(u16x8*)(tmp + 8);
  }
  __syncthreads();
  int lane = t & 63, wave = t >> 6;
  int row = lane & 15, quad = lane >> 4;
  int nh = wave * 32;
  f32x4 acc[2][4];
#pragma unroll
  for (int i = 0; i < 2; i++)
#pragma unroll
    for (int j = 0; j < 4; j++) acc[i][j] = (f32x4){0.f, 0.f, 0.f, 0.f};
  s16x8 af[4], bf[2];
#pragma unroll
  for (int mt = 0; mt < 4; mt++) {
    int R = mt * 16 + row;
    af[mt] = *(const s16x8*)(As + R * 80 + quad * 16);
  }
#pragma unroll
  for (int nt = 0; nt < 2; nt++) {
    int R = nh + nt * 16 + row;
    bf[nt] = *(const s16x8*)(Bs + R * 80 + quad * 16);
  }
#pragma unroll
  for (int nt = 0; nt < 2; nt++)
#pragma unroll
    for (int mt = 0; mt < 4; mt++)
      acc[nt][mt] = __builtin_amdgcn_mfma_f32_16x16x32_bf16(af[mt], bf[nt], acc[nt][mt], 0, 0, 0);
#pragma unroll
  for (int nt = 0; nt < 2; nt++) {
    int n = nh + nt * 16 + row;
    float bv = bias[n];
#pragma unroll
    for (int mt = 0; mt < 4; mt++) {
#pragma unroll
      for (int r4 = 0; r4 < 4; r4++) {
        int m = m0 + mt * 16 + quad * 4 + r4;
        if (m < N) out[(size_t)m * 128 + n] = f2b(acc[nt][mt][r4] + bv);
      }
    }
  }
}

// ---------------------------------------------------------------- gathers (plain loads/stores)
#define ACC8(v)                                   \
  do {                                            \
    a0 += blo((v).x); a1 += bhi((v).x);           \
    a2 += blo((v).y); a3 += bhi((v).y);           \
    a4 += blo((v).z); a5 += bhi((v).z);           \
    a6 += blo((v).w); a7 += bhi((v).w);           \
  } while (0)

__global__ __launch_bounds__(256) void rgcn_gather(
    const unsigned short* __restrict__ hb, const int* __restrict__ csr,
    const int* __restrict__ seg_start, const int* __restrict__ cnt,
    const float* __restrict__ inv, const int* __restrict__ perm,
    unsigned short* __restrict__ ahat, int total) {
  int half = blockIdx.x & 1;
  int i = (blockIdx.x >> 1) * 32 + (threadIdx.x >> 3);
  if (i >= total) return;
  int n = perm[i];
  if (n < 0) return;
  int c8 = half * 64 + (threadIdx.x & 7) * 8;
  int4 st4 = *(const int4*)(seg_start + (size_t)n * 4);
  int4 cn4 = *(const int4*)(cnt + (size_t)n * 4);
  float4 w4 = *(const float4*)(inv + (size_t)n * 4);
  int sts[4] = {st4.x, st4.y, st4.z, st4.w};
  int cns[4] = {cn4.x, cn4.y, cn4.z, cn4.w};
  float ws[4] = {w4.x, w4.y, w4.z, w4.w};
#pragma unroll
  for (int r = 0; r < 4; r++) {
    int st = sts[r], cn = cns[r];
    float w = ws[r];
    float a0 = 0.f, a1 = 0.f, a2 = 0.f, a3 = 0.f, a4 = 0.f, a5 = 0.f, a6 = 0.f, a7 = 0.f;
    int ii = 0;
    for (; ii + 4 <= cn; ii += 4) {
      int p0 = csr[st + ii], p1 = csr[st + ii + 1];
      int p2 = csr[st + ii + 2], p3 = csr[st + ii + 3];
      uint4 v0 = *(const uint4*)(hb + (size_t)p0 * 128 + c8);
      uint4 v1 = *(const uint4*)(hb + (size_t)p1 * 128 + c8);
      uint4 v2 = *(const uint4*)(hb + (size_t)p2 * 128 + c8);
      uint4 v3 = *(const uint4*)(hb + (size_t)p3 * 128 + c8);
      ACC8(v0);
      ACC8(v1);
      ACC8(v2);
      ACC8(v3);
    }
    if (ii + 2 <= cn) {
      int p0 = csr[st + ii], p1 = csr[st + ii + 1];
      uint4 v0 = *(const uint4*)(hb + (size_t)p0 * 128 + c8);
      uint4 v1 = *(const uint4*)(hb + (size_t)p1 * 128 + c8);
      ACC8(v0);
      ACC8(v1);
      ii += 2;
    }
    if (ii < cn) {
      uint4 v0 = *(const uint4*)(hb + (size_t)csr[st + ii] * 128 + c8);
      ACC8(v0);
    }
    uint4 o;
    o.x = (unsigned int)f2b(a0 * w) | ((unsigned int)f2b(a1 * w) << 16);
    o.y = (unsigned int)f2b(a2 * w) | ((unsigned int)f2b(a3 * w) << 16);
    o.z = (unsigned int)f2b(a4 * w) | ((unsigned int)f2b(a5 * w) << 16);
    o.w = (unsigned int)f2b(a6 * w) | ((unsigned int)f2b(a7 * w) << 16);
    *(uint4*)(ahat + (size_t)i * 512 + r * 128 + c8) = o;
  }
}

__global__ __launch_bounds__(256) void mf_gather(
    const unsigned short* __restrict__ hb, const int* __restrict__ csr,
    const int* __restrict__ seg_start, const int* __restrict__ deg,
    const int* __restrict__ perm, unsigned short* __restrict__ amf, int total) {
  int half = blockIdx.x & 1;
  int i = (blockIdx.x >> 1) * 32 + (threadIdx.x >> 3);
  if (i >= total) return;
  int n = perm[i];
  if (n < 0) return;
  int c8 = half * 64 + (threadIdx.x & 7) * 8;
  int st = seg_start[n * 4], dg = deg[n];
  float a0 = 0.f, a1 = 0.f, a2 = 0.f, a3 = 0.f, a4 = 0.f, a5 = 0.f, a6 = 0.f, a7 = 0.f;
  int i2 = 0;
  for (; i2 + 4 <= dg; i2 += 4) {
    int p0 = csr[st + i2], p1 = csr[st + i2 + 1];
    int p2 = csr[st + i2 + 2], p3 = csr[st + i2 + 3];
    uint4 v0 = *(const uint4*)(hb + (size_t)p0 * 128 + c8);
    uint4 v1 = *(const uint4*)(hb + (size_t)p1 * 128 + c8);
    uint4 v2 = *(const uint4*)(hb + (size_t)p2 * 128 + c8);
    uint4 v3 = *(const uint4*)(hb + (size_t)p3 * 128 + c8);
    ACC8(v0);
    ACC8(v1);
    ACC8(v2);
    ACC8(v3);
  }
  if (i2 + 2 <= dg) {
    int p0 = csr[st + i2], p1 = csr[st + i2 + 1];
    uint4 v0 = *(const uint4*)(hb + (size_t)p0 * 128 + c8);
    uint4 v1 = *(const uint4*)(hb + (size_t)p1 * 128 + c8);
    ACC8(v0);
    ACC8(v1);
    i2 += 2;
  }
  if (i2 < dg) {
    uint4 v0 = *(const uint4*)(hb + (size_t)csr[st + i2] * 128 + c8);
    ACC8(v0);
  }
  uint4 o;
  o.x = (unsigned int)f2b(a0) | ((unsigned int)f2b(a1) << 16);
  o.y = (unsigned int)f2b(a2) | ((unsigned int)f2b(a3) << 16);
  o.z = (unsigned int)f2b(a4) | ((unsigned int)f2b(a5) << 16);
  o.w = (unsigned int)f2b(a6) | ((unsigned int)f2b(a7) << 16);
  *(uint4*)(amf + (size_t)i * 128 + c8) = o;
}

// ---------------------------------------------------------------- tiled MFMA GEMMs (64-row blocks)
__global__ __launch_bounds__(256) void rgcn_mfma(const unsigned short* __restrict__ A,
                                                 const unsigned short* __restrict__ hroot,
                                                 const unsigned short* __restrict__ Bt,
                                                 const float* __restrict__ bias,
                                                 const int* __restrict__ perm,
                                                 unsigned short* __restrict__ out) {
  __shared__ unsigned char As[8192];
  __shared__ unsigned char Bs[16384];
  __shared__ int nodes[64];
  int t = threadIdx.x;
  int m0 = blockIdx.x * 64;
  if (t >= 64 && t < 128) nodes[t - 64] = perm[m0 + t - 64];
  __syncthreads();
  int lane = t & 63, wave = t >> 6;
  int row = lane & 15, quad = lane >> 4;
  int nh = wave * 32;
  f32x4 acc[2][4];
#pragma unroll
  for (int i = 0; i < 2; i++)
#pragma unroll
    for (int j = 0; j < 4; j++) acc[i][j] = (f32x4){0.f, 0.f, 0.f, 0.f};

  for (int kt = 0; kt < 10; kt++) {
    int kb2 = kt * 128;
#pragma unroll
    for (int s = 0; s < 2; s++) {
      int o = s * 4096 + t * 16;
      int r = o >> 7, c = ((o >> 4) & 7) ^ (r & 7);
      const char* gsrc;
      if (kt < 8) {
        gsrc = (const char*)A + (size_t)(m0 + r) * 1024 + kb2 + c * 16;
      } else {
        int nd = nodes[r];
        if (nd < 0) nd = 0;
        gsrc = (const char*)hroot + (size_t)nd * 256 + (kb2 - 1024) + c * 16;
      }
      gld_lds16(gsrc, As + o);
    }
#pragma unroll
    for (int s = 0; s < 4; s++) {
      int o = s * 4096 + t * 16;
      int r = o >> 7, c = ((o >> 4) & 7) ^ (r & 7);
      gld_lds16((const char*)Bt + (size_t)r * 1280 + kb2 + c * 16, Bs + o);
    }
    __syncthreads();
#pragma unroll
    for (int ks = 0; ks < 2; ks++) {
      int cch = ks * 4 + quad;
      s16x8 af[4], bf[2];
#pragma unroll
      for (int mt = 0; mt < 4; mt++) {
        int R = mt * 16 + row;
        af[mt] = *(const s16x8*)(As + R * 128 + ((cch ^ (R & 7)) << 4));
      }
#pragma unroll
      for (int nt = 0; nt < 2; nt++) {
        int R = nh + nt * 16 + row;
        bf[nt] = *(const s16x8*)(Bs + R * 128 + ((cch ^ (R & 7)) << 4));
      }
#pragma unroll
      for (int nt = 0; nt < 2; nt++)
#pragma unroll
        for (int mt = 0; mt < 4; mt++)
          acc[nt][mt] = __builtin_amdgcn_mfma_f32_16x16x32_bf16(af[mt], bf[nt], acc[nt][mt], 0, 0, 0);
    }
    __syncthreads();
  }
#pragma unroll
  for (int nt = 0; nt < 2; nt++) {
    int n = nh + nt * 16 + row;
    float bv = bias[n];
#pragma unroll
    for (int mt = 0; mt < 4; mt++) {
#pragma unroll
      for (int r4 = 0; r4 < 4; r4++) {
        int nd = nodes[mt * 16 + quad * 4 + r4];
        if (nd >= 0) out[(size_t)nd * 128 + n] = f2b(fmaxf(acc[nt][mt][r4] + bv, 0.f));
      }
    }
  }
}

__global__ __launch_bounds__(256) void mf_mfma(const unsigned short* __restrict__ A,
                                               const unsigned short* __restrict__ hroot,
                                               const unsigned short* __restrict__ Bt,
                                               const float* __restrict__ bl,
                                               const int* __restrict__ perm,
                                               const int* __restrict__ hist,
                                               unsigned short* __restrict__ out, int relu_out) {
  __shared__ unsigned char As[8192];
  __shared__ unsigned char Bs[16384];
  __shared__ int soff[NBUCK + 1];
  __shared__ int nodes[64];
  int t = threadIdx.x;
  int m0 = blockIdx.x * 64;
  if (t == 0) {
    int acc = 0;
    for (int b2 = 0; b2 < NBUCK; b2++) {
      soff[b2] = acc;
      acc += ((hist[b2] + 63) >> 6) << 6;
    }
    soff[NBUCK] = acc;
  }
  if (t >= 64 && t < 128) nodes[t - 64] = perm[m0 + t - 64];
  __syncthreads();
  if (m0 >= soff[NBUCK]) return;
  int b = 0;
  while (b < 10 && m0 >= soff[b + 1]) b++;
  const unsigned short* Bb = Bt + (size_t)b * 128 * 256;
  const float* bb = bl + b * 128;
  int lane = t & 63, wave = t >> 6;
  int row = lane & 15, quad = lane >> 4;
  int nh = wave * 32;
  f32x4 acc[2][4];
#pragma unroll
  for (int i = 0; i < 2; i++)
#pragma unroll
    for (int j = 0; j < 4; j++) acc[i][j] = (f32x4){0.f, 0.f, 0.f, 0.f};

  for (int kt = 0; kt < 4; kt++) {
    int kb2 = kt * 128;
#pragma unroll
    for (int s = 0; s < 2; s++) {
      int o = s * 4096 + t * 16;
      int r = o >> 7, c = ((o >> 4) & 7) ^ (r & 7);
      const char* gsrc;
      if (kt < 2) {
        gsrc = (const char*)A + (size_t)(m0 + r) * 256 + kb2 + c * 16;
      } else {
        int nd = nodes[r];
        if (nd < 0) nd = 0;
        gsrc = (const char*)hroot + (size_t)nd * 256 + (kb2 - 512) + c * 16;
      }
      gld_lds16(gsrc, As + o);
    }
#pragma unroll
    for (int s = 0; s < 4; s++) {
      int o = s * 4096 + t * 16;
      int r = o >> 7, c = ((o >> 4) & 7) ^ (r & 7);
      gld_lds16((const char*)Bb + (size_t)r * 512 + kb2 + c * 16, Bs + o);
    }
    __syncthreads();
#pragma unroll
    for (int ks = 0; ks < 2; ks++) {
      int cch = ks * 4 + quad;
      s16x8 af[4], bf[2];
#pragma unroll
      for (int mt = 0; mt < 4; mt++) {
        int R = mt * 16 + row;
        af[mt] = *(const s16x8*)(As + R * 128 + ((cch ^ (R & 7)) << 4));
      }
#pragma unroll
      for (int nt = 0; nt < 2; nt++) {
        int R = nh + nt * 16 + row;
        bf[nt] = *(const s16x8*)(Bs + R * 128 + ((cch ^ (R & 7)) << 4));
      }
#pragma unroll
      for (int nt = 0; nt < 2; nt++)
#pragma unroll
        for (int mt = 0; mt < 4; mt++)
          acc[nt][mt] = __builtin_amdgcn_mfma_f32_16x16x32_bf16(af[mt], bf[nt], acc[nt][mt], 0, 0, 0);
    }
    __syncthreads();
  }
#pragma unroll
  for (int nt = 0; nt < 2; nt++) {
    int n = nh + nt * 16 + row;
    float bv = bb[n];
#pragma unroll
    for (int mt = 0; mt < 4; mt++) {
#pragma unroll
      for (int r4 = 0; r4 < 4; r4++) {
        int nd = nodes[mt * 16 + quad * 4 + r4];
        if (nd >= 0) {
          float v = acc[nt][mt][r4] + bv;
          if (relu_out) v = fmaxf(v, 0.f);
          out[(size_t)nd * 128 + n] = f2b(v);
        }
      }
    }
  }
}

// ---------------------------------------------------------------- pool + head
__global__ void pool2(const unsigned short* __restrict__ h, const int* __restrict__ batch,
                      float* __restrict__ g, int N, int G) {
  int gr = blockIdx.x / POOL_CHUNKS;
  int ck = blockIdx.x % POOL_CHUNKS;
  int t = threadIdx.x;
  int lane = t & 63, grp = t >> 6;
  int lo = 0, hi = N;
  while (lo < hi) {
    int m = (lo + hi) >> 1;
    if (batch[m] < gr) lo = m + 1; else hi = m;
  }
  int s = lo;
  lo = s; hi = N;
  while (lo < hi) {
    int m = (lo + hi) >> 1;
    if (batch[m] < gr + 1) lo = m + 1; else hi = m;
  }
  int e = lo;
  int len = e - s;
  int a = s + (int)(((long long)len * ck) / POOL_CHUNKS);
  int b = s + (int)(((long long)len * (ck + 1)) / POOL_CHUNKS);
  float s0 = 0.f, s1 = 0.f;
  for (int n = a + grp; n < b; n += 2) {
    unsigned int v = *(const unsigned int*)(h + (size_t)n * 128 + lane * 2);
    s0 += blo(v);
    s1 += bhi(v);
  }
  if (b > a + grp) {
    atomicAdd(&g[gr * 128 + lane * 2], s0);
    atomicAdd(&g[gr * 128 + lane * 2 + 1], s1);
  }
}

__global__ void head_kernel(const float* __restrict__ g, const float* __restrict__ W1,
                            const float* __restrict__ b1, const float* __restrict__ W2,
                            const float* __restrict__ b2, float* __restrict__ out) {
  int bg = blockIdx.x;
  int o = threadIdx.x;
  __shared__ float gs[128];
  __shared__ float red[128];
  gs[o] = g[bg * 128 + o];
  __syncthreads();
  float acc = b1[o];
  for (int k = 0; k < 128; k++) acc += gs[k] * W1[k * 128 + o];
  acc = fmaxf(acc, 0.f);
  red[o] = acc * W2[o];
  __syncthreads();
  for (int s = 64; s > 0; s >>= 1) {
    if (o < s) red[o] += red[o + s];
    __syncthreads();
  }
  if (o == 0) out[bg] = red[0] + b2[0];
}

// ---------------------------------------------------------------- launch
extern "C" void kernel_launch(void* const* d_in, const int* in_sizes, int n_in,
                              void* d_out, int out_size, void* d_ws, size_t ws_size,
                              hipStream_t stream) {
  const float* x = (const float*)d_in[0];
  const int* ei = (const int*)d_in[1];
  const int* ea = (const int*)d_in[2];
  const int* batch = (const int*)d_in[3];
  const float* embW = (const float*)d_in[4];
  const float* embB = (const float*)d_in[5];
  const float* Wrel = (const float*)d_in[6];
  const float* Wroot = (const float*)d_in[7];
  const float* rb = (const float*)d_in[8];
  const float* Wl = (const float*)d_in[9];
  const float* bl = (const float*)d_in[10];
  const float* Wr = (const float*)d_in[11];
  const float* l1W = (const float*)d_in[12];
  const float* l1b = (const float*)d_in[13];
  const float* l2W = (const float*)d_in[14];
  const float* l2b = (const float*)d_in[15];
  float* out = (float*)d_out;

  int N = in_sizes[0] / 32;
  int E = in_sizes[2];
  int G = out_size;
  int NSEG = N * 4;
  int NB = (N + 127) >> 7;

  char* p = (char*)d_ws;
  auto alloc = [&](size_t bytes) {
    char* r = p;
    p += (bytes + 255) & ~(size_t)255;
    return r;
  };
  int permCap = ((N + 63) / 64 + NBUCK) * 64;
  unsigned short* h_bf = (unsigned short*)alloc((size_t)N * 128 * 2);
  unsigned short* h2_bf = (unsigned short*)alloc((size_t)N * 128 * 2);
  unsigned short* ahat = (unsigned short*)alloc((size_t)permCap * 512 * 2);
  unsigned short* amf = (unsigned short*)alloc((size_t)permCap * 128 * 2);
  unsigned short* Btr = (unsigned short*)alloc((size_t)2 * 128 * 640 * 2);
  unsigned short* Btm = (unsigned short*)alloc((size_t)2 * 11 * 128 * 256 * 2);
  float* inv = (float*)alloc((size_t)NSEG * 4);
  int* cnt = (int*)alloc((size_t)NSEG * 4);
  int* seg_start = (int*)alloc((size_t)NSEG * 4);
  int* csr = (int*)alloc((size_t)E * 4);
  uint2* ebuf = (uint2*)alloc((size_t)E * 8);
  int* deg = (int*)alloc((size_t)N * 4);
  int* bucket = (int*)alloc((size_t)N * 4);
  int* perm = (int*)alloc((size_t)permCap * 4);
  int* boff = (int*)alloc(516 * 4);
  int* bcur = (int*)alloc(512 * 4);
  size_t zeroBytes = 8192 + (size_t)G * 128 * 4;
  char* zb = alloc(zeroBytes);
  int* bhist = (int*)zb;
  int* hist = (int*)(zb + 4096);
  int* fill = (int*)(zb + 4224);
  int* done = (int*)(zb + 4352);
  float* g = (float*)(zb + 8192);

  (void)hipMemsetAsync(zb, 0, zeroBytes, stream);

  const int* src = ei;
  const int* dst = ei + E;

  int sblocks = (E + 4095) / 4096;
  coarse_count_scan<<<sblocks, 512, 0, stream>>>(dst, bhist, boff, bcur, done, perm, permCap,
                                                 NB, E, sblocks);
  coarse_scatter<<<sblocks, 512, 0, stream>>>(src, dst, ea, bcur, ebuf, E);
  fine_place<<<NB, 512, 0, stream>>>(ebuf, boff, cnt, seg_start, inv, deg, bucket, hist, csr,
                                     NSEG);
  build_perm<<<(N + 255) / 256, 256, 0, stream>>>(bucket, hist, fill, perm, N);

  int nbE = (N + 63) / 64;
  int convBlocks = (2 * 128 * 640 + 2 * 11 * 128 * 256 + 255) / 256;
  embed_conv<<<nbE + convBlocks, 256, 0, stream>>>(x, embW, embB, Wrel, Wroot, Wl, Wr, Btr,
                                                   Btm, h_bf, N, nbE);

  int mfblocks = permCap / 64;
  int gblocks = ((permCap + 31) / 32) * 2;
  for (int blk = 0; blk < 2; blk++) {
    rgcn_gather<<<gblocks, 256, 0, stream>>>(h_bf, csr, seg_start, cnt, inv, perm, ahat,
                                             permCap);
    rgcn_mfma<<<mfblocks, 256, 0, stream>>>(ahat, h_bf, Btr + (size_t)blk * 81920,
                                            rb + blk * 128, perm, h2_bf);
    mf_gather<<<gblocks, 256, 0, stream>>>(h2_bf, csr, seg_start, deg, perm, amf, permCap);
    mf_mfma<<<mfblocks, 256, 0, stream>>>(amf, h2_bf, Btm + (size_t)blk * 11 * 128 * 256,
                                          bl + (size_t)blk * 11 * 128, perm, hist, h_bf,
                                          (blk == 0) ? 1 : 0);
  }
  pool2<<<G * POOL_CHUNKS, 128, 0, stream>>>(h_bf, batch, g, N, G);
  head_kernel<<<G, 128, 0, stream>>>(g, l1W, l1b, l2W, l2b, out);
}